// Round 1
// baseline (544.937 us; speedup 1.0000x reference)
//
#include <hip/hip_runtime.h>
#include <hip/hip_bf16.h>

// Problem constants
#define Bsz 4
#define Tseq 2048
#define Cdim 1024
#define NH 16
#define HD 64
#define Mrows (Bsz*Tseq)      // 8192
#define N3C (3*Cdim)          // 3072

typedef __attribute__((ext_vector_type(8))) short short8;
typedef __attribute__((ext_vector_type(4))) float float4v;

__device__ __forceinline__ unsigned short f2b(float f) {
    union { float f; unsigned u; } x; x.f = f;
    unsigned u = x.u;
    u += 0x7fff + ((u >> 16) & 1);   // RNE to bf16
    return (unsigned short)(u >> 16);
}

// ---------------- cast x: f32 -> bf16 ----------------
__global__ __launch_bounds__(256) void cast_kernel(const float* __restrict__ in,
                                                   unsigned short* __restrict__ out, int n) {
    int i = (blockIdx.x * 256 + threadIdx.x) * 4;
    if (i < n) {
        float4 v = *reinterpret_cast<const float4*>(in + i);
        ushort4 o;
        o.x = f2b(v.x); o.y = f2b(v.y); o.z = f2b(v.z); o.w = f2b(v.w);
        *reinterpret_cast<ushort4*>(out + i) = o;
    }
}

// ---------------- transpose + cast: W[K][N] f32 -> Wt[N][K] bf16 ----------------
__global__ __launch_bounds__(256) void transpose_cast(const float* __restrict__ in,
                                                      unsigned short* __restrict__ out,
                                                      int K, int N) {
    __shared__ float tile[32][33];
    int n0 = blockIdx.x * 32, k0 = blockIdx.y * 32;
    int tx = threadIdx.x & 31, ty = threadIdx.x >> 5;   // 8 rows per pass
    #pragma unroll
    for (int i = 0; i < 32; i += 8)
        tile[ty + i][tx] = in[(k0 + ty + i) * N + n0 + tx];
    __syncthreads();
    #pragma unroll
    for (int i = 0; i < 32; i += 8)
        out[(size_t)(n0 + ty + i) * K + k0 + tx] = f2b(tile[tx][ty + i]);
}

// ---------------- bf16 MFMA GEMM: C[M,N] = A[M,K] * Bt[N,K]^T ----------------
// 128x128 tile, BK=32, 4 waves in 2x2, each wave 64x64 (4x4 MFMA 16x16x32)
#define LDA 40   // padded LDS stride (elems); 80B rows -> 2-way conflicts only, 16B aligned

template<bool QKV>
__global__ __launch_bounds__(256) void gemm_bt(const unsigned short* __restrict__ A,
                                               const unsigned short* __restrict__ Bt,
                                               const float* __restrict__ bias,
                                               unsigned short* __restrict__ qb,
                                               unsigned short* __restrict__ kb,
                                               unsigned short* __restrict__ vb,
                                               float* __restrict__ out) {
    __shared__ unsigned short As[128 * LDA];
    __shared__ unsigned short Bs[128 * LDA];
    int tid = threadIdx.x;
    int lane = tid & 63, wave = tid >> 6;
    int wm = wave >> 1, wn = wave & 1;
    int l15 = lane & 15, quad = lane >> 4;
    int row0 = blockIdx.y * 128;
    int col0 = blockIdx.x * 128;

    int ar = tid >> 1, ak = (tid & 1) * 16;   // staging: 2 threads/row, 16 elems each
    const unsigned short* Ag = A + (size_t)(row0 + ar) * Cdim + ak;
    const unsigned short* Bg = Bt + (size_t)(col0 + ar) * Cdim + ak;

    float4v acc[4][4] = {};

    for (int k0 = 0; k0 < Cdim; k0 += 32) {
        __syncthreads();
        *(short8*)&As[ar * LDA + ak]     = *(const short8*)(Ag + k0);
        *(short8*)&As[ar * LDA + ak + 8] = *(const short8*)(Ag + k0 + 8);
        *(short8*)&Bs[ar * LDA + ak]     = *(const short8*)(Bg + k0);
        *(short8*)&Bs[ar * LDA + ak + 8] = *(const short8*)(Bg + k0 + 8);
        __syncthreads();

        short8 af[4], bf[4];
        #pragma unroll
        for (int mi = 0; mi < 4; mi++)
            af[mi] = *(const short8*)&As[(wm * 64 + mi * 16 + l15) * LDA + quad * 8];
        #pragma unroll
        for (int ni = 0; ni < 4; ni++)
            bf[ni] = *(const short8*)&Bs[(wn * 64 + ni * 16 + l15) * LDA + quad * 8];
        #pragma unroll
        for (int mi = 0; mi < 4; mi++)
            #pragma unroll
            for (int ni = 0; ni < 4; ni++)
                acc[mi][ni] = __builtin_amdgcn_mfma_f32_16x16x32_bf16(af[mi], bf[ni], acc[mi][ni], 0, 0, 0);
    }

    // epilogue
    #pragma unroll
    for (int mi = 0; mi < 4; mi++) {
        #pragma unroll
        for (int ni = 0; ni < 4; ni++) {
            #pragma unroll
            for (int r = 0; r < 4; r++) {
                int row = row0 + wm * 64 + mi * 16 + quad * 4 + r;
                int col = col0 + wn * 64 + ni * 16 + l15;
                float v = acc[mi][ni][r] + bias[col];
                if (QKV) {
                    int p = col >> 10;          // 0=q 1=k 2=v
                    int h = (col & 1023) >> 6;
                    int d = col & 63;
                    int b = row >> 11;
                    int t = row & 2047;
                    size_t idx = ((size_t)(b * NH + h) * Tseq + t) * HD + d;
                    unsigned short bv = f2b(v);
                    if (p == 0) qb[idx] = bv;
                    else if (p == 1) kb[idx] = bv;
                    else vb[idx] = bv;
                } else {
                    out[(size_t)row * Cdim + col] = v;
                }
            }
        }
    }
}

// ---------------- flash attention (causal), bf16 MFMA ----------------
// block = 256 thr (4 waves); block handles 64 q-rows of one (b,h); kv tiles of 64
#define LDK 72   // padded LDS stride: 144B rows, 16B aligned, 2-way conflict reads

__global__ __launch_bounds__(256) void attn_kernel(const unsigned short* __restrict__ qb,
                                                   const unsigned short* __restrict__ kb,
                                                   const unsigned short* __restrict__ vb,
                                                   unsigned short* __restrict__ yb) {
    __shared__ unsigned short Ks[64 * LDK];
    __shared__ unsigned short Vt[64 * LDK];
    __shared__ unsigned short Ps[4][16 * LDK];

    int tid = threadIdx.x;
    int lane = tid & 63, wave = tid >> 6;
    int l15 = lane & 15, quad = lane >> 4;
    int bh = blockIdx.y;
    int q0 = blockIdx.x * 64;

    const unsigned short* Qh = qb + (size_t)bh * Tseq * HD;
    const unsigned short* Kh = kb + (size_t)bh * Tseq * HD;
    const unsigned short* Vh = vb + (size_t)bh * Tseq * HD;

    // Q fragments in registers: wave handles q rows [q0+wave*16, +16)
    int qrow = q0 + wave * 16 + l15;
    short8 qf0 = *(const short8*)(Qh + (size_t)qrow * HD + quad * 8);
    short8 qf1 = *(const short8*)(Qh + (size_t)qrow * HD + 32 + quad * 8);

    float4v ov[4] = {};
    float m[4], l[4];
    #pragma unroll
    for (int r = 0; r < 4; r++) { m[r] = -1e30f; l[r] = 0.f; }
    const float cexp = 0.18033688011112042f;   // 0.125 * log2(e)

    int key = tid >> 2, d0 = (tid & 3) * 16;   // staging mapping
    int ntiles = blockIdx.x + 1;

    for (int jt = 0; jt < ntiles; ++jt) {
        int j0 = jt * 64;
        __syncthreads();
        // stage K tile [key][d]
        const unsigned short* Kg = Kh + (size_t)(j0 + key) * HD + d0;
        *(short8*)&Ks[key * LDK + d0]     = *(const short8*)(Kg);
        *(short8*)&Ks[key * LDK + d0 + 8] = *(const short8*)(Kg + 8);
        // stage V transposed: Vt[d][key]
        const unsigned short* Vg = Vh + (size_t)(j0 + key) * HD + d0;
        short8 v0 = *(const short8*)(Vg);
        short8 v1 = *(const short8*)(Vg + 8);
        #pragma unroll
        for (int i = 0; i < 8; i++) {
            Vt[(d0 + i) * LDK + key] = ((unsigned short*)&v0)[i];
            Vt[(d0 + 8 + i) * LDK + key] = ((unsigned short*)&v1)[i];
        }
        __syncthreads();

        // S = Q * K^T   (16 q-rows x 64 keys per wave)
        float4v sa[4] = {};
        #pragma unroll
        for (int ni = 0; ni < 4; ni++) {
            short8 b0 = *(const short8*)&Ks[(ni * 16 + l15) * LDK + quad * 8];
            short8 b1 = *(const short8*)&Ks[(ni * 16 + l15) * LDK + 32 + quad * 8];
            sa[ni] = __builtin_amdgcn_mfma_f32_16x16x32_bf16(qf0, b0, sa[ni], 0, 0, 0);
            sa[ni] = __builtin_amdgcn_mfma_f32_16x16x32_bf16(qf1, b1, sa[ni], 0, 0, 0);
        }

        // causal mask on diagonal tile
        if (jt == ntiles - 1) {
            #pragma unroll
            for (int ni = 0; ni < 4; ni++)
                #pragma unroll
                for (int r = 0; r < 4; r++) {
                    int rg = q0 + wave * 16 + quad * 4 + r;
                    int cg = j0 + ni * 16 + l15;
                    if (cg > rg) sa[ni][r] = -1e30f;
                }
        }

        // online softmax (rows = quad*4+r, cols spread over 16 lanes x 4 ni)
        #pragma unroll
        for (int r = 0; r < 4; r++) {
            float mx = fmaxf(fmaxf(sa[0][r], sa[1][r]), fmaxf(sa[2][r], sa[3][r]));
            mx = fmaxf(mx, __shfl_xor(mx, 1));
            mx = fmaxf(mx, __shfl_xor(mx, 2));
            mx = fmaxf(mx, __shfl_xor(mx, 4));
            mx = fmaxf(mx, __shfl_xor(mx, 8));
            float mn = fmaxf(m[r], mx);
            float a_ = exp2f((m[r] - mn) * cexp);
            float sum = 0.f;
            #pragma unroll
            for (int ni = 0; ni < 4; ni++) {
                float p = exp2f((sa[ni][r] - mn) * cexp);
                sa[ni][r] = p;
                sum += p;
            }
            sum += __shfl_xor(sum, 1);
            sum += __shfl_xor(sum, 2);
            sum += __shfl_xor(sum, 4);
            sum += __shfl_xor(sum, 8);
            l[r] = l[r] * a_ + sum;
            m[r] = mn;
            #pragma unroll
            for (int ni = 0; ni < 4; ni++) ov[ni][r] *= a_;
        }

        // P (C-layout) -> LDS -> A-layout fragments (per-wave region, no barrier needed)
        #pragma unroll
        for (int r = 0; r < 4; r++)
            #pragma unroll
            for (int ni = 0; ni < 4; ni++)
                Ps[wave][(quad * 4 + r) * LDK + ni * 16 + l15] = f2b(sa[ni][r]);
        asm volatile("s_waitcnt lgkmcnt(0)" ::: "memory");

        // O += P * V
        #pragma unroll
        for (int ks = 0; ks < 2; ks++) {
            short8 pf = *(const short8*)&Ps[wave][l15 * LDK + ks * 32 + quad * 8];
            #pragma unroll
            for (int ni = 0; ni < 4; ni++) {
                short8 vf = *(const short8*)&Vt[(ni * 16 + l15) * LDK + ks * 32 + quad * 8];
                ov[ni] = __builtin_amdgcn_mfma_f32_16x16x32_bf16(pf, vf, ov[ni], 0, 0, 0);
            }
        }
    }

    // epilogue: y[b][t][h*64+d] bf16
    int b = bh >> 4, h = bh & 15;
    #pragma unroll
    for (int ni = 0; ni < 4; ni++)
        #pragma unroll
        for (int r = 0; r < 4; r++) {
            int rg = q0 + wave * 16 + quad * 4 + r;
            float o = ov[ni][r] / l[r];
            yb[((size_t)b * Tseq + rg) * Cdim + h * HD + ni * 16 + l15] = f2b(o);
        }
}

extern "C" void kernel_launch(void* const* d_in, const int* in_sizes, int n_in,
                              void* d_out, int out_size, void* d_ws, size_t ws_size,
                              hipStream_t stream) {
    const float* x  = (const float*)d_in[0];
    const float* Wa = (const float*)d_in[1];
    const float* ba = (const float*)d_in[2];
    const float* Wp = (const float*)d_in[3];
    const float* bp = (const float*)d_in[4];
    float* out = (float*)d_out;

    unsigned short* ws = (unsigned short*)d_ws;
    unsigned short* xb  = ws;                          // 8192*1024
    unsigned short* Wat = xb  + (size_t)Mrows * Cdim;  // 3072*1024
    unsigned short* Wpt = Wat + (size_t)N3C * Cdim;    // 1024*1024
    unsigned short* qb  = Wpt + (size_t)Cdim * Cdim;   // 64*2048*64
    unsigned short* kb  = qb  + (size_t)Bsz * NH * Tseq * HD;
    unsigned short* vb  = kb  + (size_t)Bsz * NH * Tseq * HD;
    unsigned short* yb  = vb  + (size_t)Bsz * NH * Tseq * HD;

    int nx = Mrows * Cdim;
    cast_kernel<<<nx / 4 / 256, 256, 0, stream>>>(x, xb, nx);
    transpose_cast<<<dim3(N3C / 32, Cdim / 32), 256, 0, stream>>>(Wa, Wat, Cdim, N3C);
    transpose_cast<<<dim3(Cdim / 32, Cdim / 32), 256, 0, stream>>>(Wp, Wpt, Cdim, Cdim);

    gemm_bt<true><<<dim3(N3C / 128, Mrows / 128), 256, 0, stream>>>(
        xb, Wat, ba, qb, kb, vb, nullptr);

    attn_kernel<<<dim3(Tseq / 64, Bsz * NH), 256, 0, stream>>>(qb, kb, vb, yb);

    gemm_bt<false><<<dim3(Cdim / 128, Mrows / 128), 256, 0, stream>>>(
        yb, Wpt, bp, nullptr, nullptr, nullptr, out);
}

// Round 2
// 486.022 us; speedup vs baseline: 1.1212x; 1.1212x over previous
//
#include <hip/hip_runtime.h>
#include <hip/hip_bf16.h>

// Problem constants
#define Bsz 4
#define Tseq 2048
#define Cdim 1024
#define NH 16
#define HD 64
#define Mrows (Bsz*Tseq)      // 8192
#define N3C (3*Cdim)          // 3072

typedef __attribute__((ext_vector_type(8))) short short8;
typedef __attribute__((ext_vector_type(4))) float float4v;

__device__ __forceinline__ unsigned short f2b(float f) {
    union { float f; unsigned u; } x; x.f = f;
    unsigned u = x.u;
    u += 0x7fff + ((u >> 16) & 1);   // RNE to bf16
    return (unsigned short)(u >> 16);
}

// ---------------- cast x: f32 -> bf16 ----------------
__global__ __launch_bounds__(256) void cast_kernel(const float* __restrict__ in,
                                                   unsigned short* __restrict__ out, int n) {
    int i = (blockIdx.x * 256 + threadIdx.x) * 4;
    if (i < n) {
        float4 v = *reinterpret_cast<const float4*>(in + i);
        ushort4 o;
        o.x = f2b(v.x); o.y = f2b(v.y); o.z = f2b(v.z); o.w = f2b(v.w);
        *reinterpret_cast<ushort4*>(out + i) = o;
    }
}

// ---------------- transpose + cast: W[K][N] f32 -> Wt[N][K] bf16 ----------------
__global__ __launch_bounds__(256) void transpose_cast(const float* __restrict__ in,
                                                      unsigned short* __restrict__ out,
                                                      int K, int N) {
    __shared__ float tile[32][33];
    int n0 = blockIdx.x * 32, k0 = blockIdx.y * 32;
    int tx = threadIdx.x & 31, ty = threadIdx.x >> 5;   // 8 rows per pass
    #pragma unroll
    for (int i = 0; i < 32; i += 8)
        tile[ty + i][tx] = in[(k0 + ty + i) * N + n0 + tx];
    __syncthreads();
    #pragma unroll
    for (int i = 0; i < 32; i += 8)
        out[(size_t)(n0 + ty + i) * K + k0 + tx] = f2b(tile[tx][ty + i]);
}

// ---------------- bf16 MFMA GEMM: C[M,N] = A[M,K] * Bt[N,K]^T ----------------
// 128x128 tile, BK=32, 4 waves in 2x2, each wave 64x64 (4x4 MFMA 16x16x32)
#define LDA 40   // padded LDS stride (elems); 80B rows -> 2-way conflicts only, 16B aligned

template<bool QKV>
__global__ __launch_bounds__(256) void gemm_bt(const unsigned short* __restrict__ A,
                                               const unsigned short* __restrict__ Bt,
                                               const float* __restrict__ bias,
                                               unsigned short* __restrict__ qb,
                                               unsigned short* __restrict__ kb,
                                               unsigned short* __restrict__ vb,
                                               float* __restrict__ out) {
    __shared__ unsigned short As[128 * LDA];
    __shared__ unsigned short Bs[128 * LDA];
    int tid = threadIdx.x;
    int lane = tid & 63, wave = tid >> 6;
    int wm = wave >> 1, wn = wave & 1;
    int l15 = lane & 15, quad = lane >> 4;
    int row0 = blockIdx.y * 128;
    int col0 = blockIdx.x * 128;

    int ar = tid >> 1, ak = (tid & 1) * 16;   // staging: 2 threads/row, 16 elems each
    const unsigned short* Ag = A + (size_t)(row0 + ar) * Cdim + ak;
    const unsigned short* Bg = Bt + (size_t)(col0 + ar) * Cdim + ak;

    float4v acc[4][4] = {};

    for (int k0 = 0; k0 < Cdim; k0 += 32) {
        __syncthreads();
        *(short8*)&As[ar * LDA + ak]     = *(const short8*)(Ag + k0);
        *(short8*)&As[ar * LDA + ak + 8] = *(const short8*)(Ag + k0 + 8);
        *(short8*)&Bs[ar * LDA + ak]     = *(const short8*)(Bg + k0);
        *(short8*)&Bs[ar * LDA + ak + 8] = *(const short8*)(Bg + k0 + 8);
        __syncthreads();

        short8 af[4], bf[4];
        #pragma unroll
        for (int mi = 0; mi < 4; mi++)
            af[mi] = *(const short8*)&As[(wm * 64 + mi * 16 + l15) * LDA + quad * 8];
        #pragma unroll
        for (int ni = 0; ni < 4; ni++)
            bf[ni] = *(const short8*)&Bs[(wn * 64 + ni * 16 + l15) * LDA + quad * 8];
        #pragma unroll
        for (int mi = 0; mi < 4; mi++)
            #pragma unroll
            for (int ni = 0; ni < 4; ni++)
                acc[mi][ni] = __builtin_amdgcn_mfma_f32_16x16x32_bf16(af[mi], bf[ni], acc[mi][ni], 0, 0, 0);
    }

    // epilogue
    #pragma unroll
    for (int mi = 0; mi < 4; mi++) {
        #pragma unroll
        for (int ni = 0; ni < 4; ni++) {
            #pragma unroll
            for (int r = 0; r < 4; r++) {
                int row = row0 + wm * 64 + mi * 16 + quad * 4 + r;
                int col = col0 + wn * 64 + ni * 16 + l15;
                float v = acc[mi][ni][r] + bias[col];
                if (QKV) {
                    int p = col >> 10;          // 0=q 1=k 2=v
                    int h = (col & 1023) >> 6;
                    int d = col & 63;
                    int b = row >> 11;
                    int t = row & 2047;
                    unsigned short bv = f2b(v);
                    if (p == 0) {
                        qb[((size_t)(b * NH + h) * Tseq + t) * HD + d] = bv;
                    } else if (p == 1) {
                        kb[((size_t)(b * NH + h) * Tseq + t) * HD + d] = bv;
                    } else {
                        // V stored TRANSPOSED: [bh][d][T] so attention can
                        // stage V^T tiles with vector loads (no LDS transpose)
                        vb[((size_t)(b * NH + h) * HD + d) * Tseq + t] = bv;
                    }
                } else {
                    out[(size_t)row * Cdim + col] = v;
                }
            }
        }
    }
}

// ---------------- flash attention (causal), bf16 MFMA ----------------
// block = 256 thr (4 waves); block handles 128 q-rows of one (b,h); wave = 32 q-rows
// kv tiles of 64 keys; V comes in pre-transposed [bh][d][T]
#define LDK 72   // padded LDS stride (shorts): 144B rows, 16B aligned

__global__ __launch_bounds__(256) void attn_kernel(const unsigned short* __restrict__ qb,
                                                   const unsigned short* __restrict__ kb,
                                                   const unsigned short* __restrict__ vt,
                                                   unsigned short* __restrict__ yb) {
    __shared__ unsigned short Ks[64 * LDK];     // [key][d]
    __shared__ unsigned short Vs[64 * LDK];     // [d][key]  (from transposed global V)
    __shared__ unsigned short Ps[4][32 * LDK];  // per-wave P round-trip (C->A layout)

    int tid = threadIdx.x;
    int lane = tid & 63, wave = tid >> 6;
    int l15 = lane & 15, quad = lane >> 4;
    int bh = blockIdx.y;
    int q0 = (gridDim.x - 1 - blockIdx.x) * 128;   // heavy blocks dispatch first

    const unsigned short* Qh = qb + (size_t)bh * Tseq * HD;
    const unsigned short* Kh = kb + (size_t)bh * Tseq * HD;
    const unsigned short* Vh = vt + (size_t)bh * HD * Tseq;

    // Q fragments in registers: wave handles q rows [q0+wave*32, +32)
    int rb0 = q0 + wave * 32;
    short8 qf[2][2];
    #pragma unroll
    for (int mi = 0; mi < 2; mi++) {
        int qrow = rb0 + mi * 16 + l15;
        qf[mi][0] = *(const short8*)(Qh + (size_t)qrow * HD + quad * 8);
        qf[mi][1] = *(const short8*)(Qh + (size_t)qrow * HD + 32 + quad * 8);
    }

    float4v ov[2][4] = {};
    float m[2][4], l[2][4];
    #pragma unroll
    for (int mi = 0; mi < 2; mi++)
        #pragma unroll
        for (int r = 0; r < 4; r++) { m[mi][r] = -1e30f; l[mi][r] = 0.f; }
    const float cexp = 0.18033688011112042f;   // 0.125 * log2(e)

    int srow = tid >> 2, sc0 = (tid & 3) * 16;   // staging: 4 threads/row, 16 elems each
    int ntiles = ((q0 + 128) >> 6);
    int rbmax = rb0 + 31;

    for (int jt = 0; jt < ntiles; ++jt) {
        int j0 = jt * 64;
        __syncthreads();
        // stage K tile [key][d] and V^T tile [d][key] — both coalesced vector loads
        const unsigned short* Kg = Kh + (size_t)(j0 + srow) * HD + sc0;
        *(short8*)&Ks[srow * LDK + sc0]     = *(const short8*)(Kg);
        *(short8*)&Ks[srow * LDK + sc0 + 8] = *(const short8*)(Kg + 8);
        const unsigned short* Vg = Vh + (size_t)srow * Tseq + j0 + sc0;
        *(short8*)&Vs[srow * LDK + sc0]     = *(const short8*)(Vg);
        *(short8*)&Vs[srow * LDK + sc0 + 8] = *(const short8*)(Vg + 8);
        __syncthreads();

        if (j0 > rbmax) continue;   // entire tile masked for this wave

        // S = Q * K^T   (32 q-rows x 64 keys per wave)
        float4v sa[2][4];
        #pragma unroll
        for (int mi = 0; mi < 2; mi++)
            #pragma unroll
            for (int ni = 0; ni < 4; ni++)
                sa[mi][ni] = (float4v){0.f, 0.f, 0.f, 0.f};
        #pragma unroll
        for (int ni = 0; ni < 4; ni++) {
            short8 b0 = *(const short8*)&Ks[(ni * 16 + l15) * LDK + quad * 8];
            short8 b1 = *(const short8*)&Ks[(ni * 16 + l15) * LDK + 32 + quad * 8];
            sa[0][ni] = __builtin_amdgcn_mfma_f32_16x16x32_bf16(qf[0][0], b0, sa[0][ni], 0, 0, 0);
            sa[0][ni] = __builtin_amdgcn_mfma_f32_16x16x32_bf16(qf[0][1], b1, sa[0][ni], 0, 0, 0);
            sa[1][ni] = __builtin_amdgcn_mfma_f32_16x16x32_bf16(qf[1][0], b0, sa[1][ni], 0, 0, 0);
            sa[1][ni] = __builtin_amdgcn_mfma_f32_16x16x32_bf16(qf[1][1], b1, sa[1][ni], 0, 0, 0);
        }

        // causal mask (only boundary tiles need it)
        #pragma unroll
        for (int mi = 0; mi < 2; mi++) {
            int rb = rb0 + mi * 16;
            if (j0 + 63 > rb) {
                #pragma unroll
                for (int ni = 0; ni < 4; ni++)
                    #pragma unroll
                    for (int r = 0; r < 4; r++) {
                        int rg = rb + quad * 4 + r;
                        int cg = j0 + ni * 16 + l15;
                        if (cg > rg) sa[mi][ni][r] = -1e30f;
                    }
            }
        }

        // online softmax (row = quad*4+r within each 16-row block; cols over l15 x ni)
        #pragma unroll
        for (int mi = 0; mi < 2; mi++)
            #pragma unroll
            for (int r = 0; r < 4; r++) {
                float mx = fmaxf(fmaxf(sa[mi][0][r], sa[mi][1][r]),
                                 fmaxf(sa[mi][2][r], sa[mi][3][r]));
                mx = fmaxf(mx, __shfl_xor(mx, 1));
                mx = fmaxf(mx, __shfl_xor(mx, 2));
                mx = fmaxf(mx, __shfl_xor(mx, 4));
                mx = fmaxf(mx, __shfl_xor(mx, 8));
                float mn = fmaxf(m[mi][r], mx);
                float a_ = exp2f((m[mi][r] - mn) * cexp);
                float sum = 0.f;
                #pragma unroll
                for (int ni = 0; ni < 4; ni++) {
                    float p = exp2f((sa[mi][ni][r] - mn) * cexp);
                    sa[mi][ni][r] = p;
                    sum += p;
                }
                sum += __shfl_xor(sum, 1);
                sum += __shfl_xor(sum, 2);
                sum += __shfl_xor(sum, 4);
                sum += __shfl_xor(sum, 8);
                l[mi][r] = l[mi][r] * a_ + sum;
                m[mi][r] = mn;
                #pragma unroll
                for (int ni = 0; ni < 4; ni++) ov[mi][ni][r] *= a_;
            }

        // P (C-layout) -> per-wave LDS -> A-layout fragments
        #pragma unroll
        for (int mi = 0; mi < 2; mi++)
            #pragma unroll
            for (int r = 0; r < 4; r++)
                #pragma unroll
                for (int ni = 0; ni < 4; ni++)
                    Ps[wave][(mi * 16 + quad * 4 + r) * LDK + ni * 16 + l15] = f2b(sa[mi][ni][r]);
        asm volatile("s_waitcnt lgkmcnt(0)" ::: "memory");

        // O += P * V
        #pragma unroll
        for (int ks = 0; ks < 2; ks++) {
            short8 pf0 = *(const short8*)&Ps[wave][(l15) * LDK + ks * 32 + quad * 8];
            short8 pf1 = *(const short8*)&Ps[wave][(16 + l15) * LDK + ks * 32 + quad * 8];
            #pragma unroll
            for (int ni = 0; ni < 4; ni++) {
                short8 vf = *(const short8*)&Vs[(ni * 16 + l15) * LDK + ks * 32 + quad * 8];
                ov[0][ni] = __builtin_amdgcn_mfma_f32_16x16x32_bf16(pf0, vf, ov[0][ni], 0, 0, 0);
                ov[1][ni] = __builtin_amdgcn_mfma_f32_16x16x32_bf16(pf1, vf, ov[1][ni], 0, 0, 0);
            }
        }
    }

    // epilogue: y[b][t][h*64+d] bf16
    int b = bh >> 4, h = bh & 15;
    #pragma unroll
    for (int mi = 0; mi < 2; mi++)
        #pragma unroll
        for (int ni = 0; ni < 4; ni++)
            #pragma unroll
            for (int r = 0; r < 4; r++) {
                int rg = rb0 + mi * 16 + quad * 4 + r;
                float o = ov[mi][ni][r] / l[mi][r];
                yb[((size_t)b * Tseq + rg) * Cdim + h * HD + ni * 16 + l15] = f2b(o);
            }
}

extern "C" void kernel_launch(void* const* d_in, const int* in_sizes, int n_in,
                              void* d_out, int out_size, void* d_ws, size_t ws_size,
                              hipStream_t stream) {
    const float* x  = (const float*)d_in[0];
    const float* Wa = (const float*)d_in[1];
    const float* ba = (const float*)d_in[2];
    const float* Wp = (const float*)d_in[3];
    const float* bp = (const float*)d_in[4];
    float* out = (float*)d_out;

    unsigned short* ws = (unsigned short*)d_ws;
    unsigned short* xb  = ws;                          // 8192*1024
    unsigned short* Wat = xb  + (size_t)Mrows * Cdim;  // 3072*1024
    unsigned short* Wpt = Wat + (size_t)N3C * Cdim;    // 1024*1024
    unsigned short* qb  = Wpt + (size_t)Cdim * Cdim;   // [bh][T][HD]
    unsigned short* kb  = qb  + (size_t)Bsz * NH * Tseq * HD;   // [bh][T][HD]
    unsigned short* vb  = kb  + (size_t)Bsz * NH * Tseq * HD;   // [bh][HD][T]  (transposed!)
    unsigned short* yb  = vb  + (size_t)Bsz * NH * Tseq * HD;

    int nx = Mrows * Cdim;
    cast_kernel<<<nx / 4 / 256, 256, 0, stream>>>(x, xb, nx);
    transpose_cast<<<dim3(N3C / 32, Cdim / 32), 256, 0, stream>>>(Wa, Wat, Cdim, N3C);
    transpose_cast<<<dim3(Cdim / 32, Cdim / 32), 256, 0, stream>>>(Wp, Wpt, Cdim, Cdim);

    gemm_bt<true><<<dim3(N3C / 128, Mrows / 128), 256, 0, stream>>>(
        xb, Wat, ba, qb, kb, vb, nullptr);

    attn_kernel<<<dim3(Tseq / 128, Bsz * NH), 256, 0, stream>>>(qb, kb, vb, yb);

    gemm_bt<false><<<dim3(Cdim / 128, Mrows / 128), 256, 0, stream>>>(
        yb, Wpt, bp, nullptr, nullptr, nullptr, out);
}

// Round 4
// 326.647 us; speedup vs baseline: 1.6683x; 1.4879x over previous
//
#include <hip/hip_runtime.h>
#include <hip/hip_bf16.h>

// Problem constants
#define Bsz 4
#define Tseq 2048
#define Cdim 1024
#define NH 16
#define HD 64
#define Mrows (Bsz*Tseq)      // 8192
#define N3C (3*Cdim)          // 3072

typedef __attribute__((ext_vector_type(8))) short short8;
typedef __attribute__((ext_vector_type(4))) short short4v;
typedef __attribute__((ext_vector_type(4))) float float4v;

__device__ __forceinline__ unsigned short f2b(float f) {
    union { float f; unsigned u; } x; x.f = f;
    unsigned u = x.u;
    u += 0x7fff + ((u >> 16) & 1);   // true RNE to bf16
    return (unsigned short)(u >> 16);
}

__device__ __forceinline__ float b2f(unsigned short us) {
    union { unsigned u; float f; } x; x.u = ((unsigned)us) << 16;
    return x.f;
}

// ---------------- cast x: f32 -> bf16 ----------------
__global__ __launch_bounds__(256) void cast_kernel(const float* __restrict__ in,
                                                   unsigned short* __restrict__ out, int n) {
    int i = (blockIdx.x * 256 + threadIdx.x) * 4;
    if (i < n) {
        float4 v = *reinterpret_cast<const float4*>(in + i);
        ushort4 o;
        o.x = f2b(v.x); o.y = f2b(v.y); o.z = f2b(v.z); o.w = f2b(v.w);
        *reinterpret_cast<ushort4*>(out + i) = o;
    }
}

// ---------------- transpose + cast: W[K][N] f32 -> Wt[N][K] bf16 ----------------
__global__ __launch_bounds__(256) void transpose_cast(const float* __restrict__ in,
                                                      unsigned short* __restrict__ out,
                                                      int K, int N) {
    __shared__ float tile[32][33];
    int n0 = blockIdx.x * 32, k0 = blockIdx.y * 32;
    int tx = threadIdx.x & 31, ty = threadIdx.x >> 5;   // 8 rows per pass
    #pragma unroll
    for (int i = 0; i < 32; i += 8)
        tile[ty + i][tx] = in[(k0 + ty + i) * N + n0 + tx];
    __syncthreads();
    #pragma unroll
    for (int i = 0; i < 32; i += 8)
        out[(size_t)(n0 + ty + i) * K + k0 + tx] = f2b(tile[tx][ty + i]);
}

// ---------------- bf16 MFMA GEMM: C[M,N] = A[M,K] * Bt[N,K]^T ----------------
// 128x128 tile, BK=32, 4 waves in 2x2, each wave 64x64 (4x4 MFMA 16x16x32)
#define LDA 40   // padded LDS stride (elems); 80B rows -> 2-way conflicts only, 16B aligned

template<bool QKV>
__global__ __launch_bounds__(256) void gemm_bt(const unsigned short* __restrict__ A,
                                               const unsigned short* __restrict__ Bt,
                                               const float* __restrict__ bias,
                                               unsigned short* __restrict__ qb,
                                               unsigned short* __restrict__ kb,
                                               unsigned short* __restrict__ vb,
                                               float* __restrict__ out) {
    __shared__ unsigned short As[128 * LDA];
    __shared__ unsigned short Bs[128 * LDA];
    int tid = threadIdx.x;
    int lane = tid & 63, wave = tid >> 6;
    int wm = wave >> 1, wn = wave & 1;
    int l15 = lane & 15, quad = lane >> 4;
    int row0 = blockIdx.y * 128;
    int col0 = blockIdx.x * 128;

    int ar = tid >> 1, ak = (tid & 1) * 16;   // staging: 2 threads/row, 16 elems each
    const unsigned short* Ag = A + (size_t)(row0 + ar) * Cdim + ak;
    const unsigned short* Bg = Bt + (size_t)(col0 + ar) * Cdim + ak;

    float4v acc[4][4] = {};

    for (int k0 = 0; k0 < Cdim; k0 += 32) {
        __syncthreads();
        *(short8*)&As[ar * LDA + ak]     = *(const short8*)(Ag + k0);
        *(short8*)&As[ar * LDA + ak + 8] = *(const short8*)(Ag + k0 + 8);
        *(short8*)&Bs[ar * LDA + ak]     = *(const short8*)(Bg + k0);
        *(short8*)&Bs[ar * LDA + ak + 8] = *(const short8*)(Bg + k0 + 8);
        __syncthreads();

        short8 af[4], bf[4];
        #pragma unroll
        for (int mi = 0; mi < 4; mi++)
            af[mi] = *(const short8*)&As[(wm * 64 + mi * 16 + l15) * LDA + quad * 8];
        #pragma unroll
        for (int ni = 0; ni < 4; ni++)
            bf[ni] = *(const short8*)&Bs[(wn * 64 + ni * 16 + l15) * LDA + quad * 8];
        #pragma unroll
        for (int mi = 0; mi < 4; mi++)
            #pragma unroll
            for (int ni = 0; ni < 4; ni++)
                acc[mi][ni] = __builtin_amdgcn_mfma_f32_16x16x32_bf16(af[mi], bf[ni], acc[mi][ni], 0, 0, 0);
    }

    // epilogue
    #pragma unroll
    for (int mi = 0; mi < 4; mi++) {
        #pragma unroll
        for (int ni = 0; ni < 4; ni++) {
            #pragma unroll
            for (int r = 0; r < 4; r++) {
                int row = row0 + wm * 64 + mi * 16 + quad * 4 + r;
                int col = col0 + wn * 64 + ni * 16 + l15;
                float v = acc[mi][ni][r] + bias[col];
                if (QKV) {
                    int p = col >> 10;          // 0=q 1=k 2=v
                    int h = (col & 1023) >> 6;
                    int d = col & 63;
                    int b = row >> 11;
                    int t = row & 2047;
                    if (p == 0) {
                        qb[((size_t)(b * NH + h) * Tseq + t) * HD + d] = f2b(v);
                    } else if (p == 1) {
                        kb[((size_t)(b * NH + h) * Tseq + t) * HD + d] = f2b(v);
                    } else {
                        // V stored TRANSPOSED: [bh][d][T]
                        vb[((size_t)(b * NH + h) * HD + d) * Tseq + t] = f2b(v);
                    }
                } else {
                    out[(size_t)row * Cdim + col] = v;
                }
            }
        }
    }
}

// ---------------- flash attention (causal), bf16 MFMA, S^T register trick ----------------
// block = 128 thr (2 waves); block processes q-tile pair (pi, 31-pi), 64 rows each,
// 32 rows/wave; kv tiles of 64 keys. No P LDS round-trip: S^T C-layout matches the
// A-operand layout of mfma_f32_16x16x16bf16_1k, so P goes register->MFMA directly.
// Numerics = round-2-proven: online row-max subtraction, p=exp2((s-m)*cexp),
// RNE bf16 P, l summed from the ROUNDED p (numerator/denominator consistent).
#define LDK 72   // padded LDS stride (shorts): 144B rows, 16B aligned

__global__ __launch_bounds__(128, 3) void attn_kernel(const unsigned short* __restrict__ qb,
                                                      const unsigned short* __restrict__ kb,
                                                      const unsigned short* __restrict__ vt,
                                                      unsigned short* __restrict__ yb) {
    __shared__ unsigned short Ks[64 * LDK];   // [key][d]
    __shared__ unsigned short Vs[64 * LDK];   // [d][key]  (from pre-transposed global V)

    int tid = threadIdx.x;
    int lane = tid & 63, wave = tid >> 6;      // 2 waves
    int l15 = lane & 15, quad = lane >> 4;
    int bh = blockIdx.y;
    int pi = blockIdx.x;                       // pair index 0..15

    const unsigned short* Qh = qb + (size_t)bh * Tseq * HD;
    const unsigned short* Kh = kb + (size_t)bh * Tseq * HD;
    const unsigned short* Vh = vt + (size_t)bh * HD * Tseq;
    int b = bh >> 4, h = bh & 15;

    int srow = tid >> 1, sc = (tid & 1) * 32;  // staging: 2 thr/row, 32 shorts each
    const float cexp = 0.18033688011112042f;   // 0.125 * log2(e)

    #pragma unroll 1
    for (int half = 0; half < 2; half++) {
        int qt = half ? (31 - pi) : pi;        // q-tile index 0..31 (64 rows)
        int q0 = qt * 64;
        int rb0 = q0 + wave * 32;              // this wave's 32 q-rows

        // Q fragments (B-operand layout: lane holds Q[qrow=l15][d=quad*8+j])
        short8 qf[2][2];
        #pragma unroll
        for (int mi = 0; mi < 2; mi++)
            #pragma unroll
            for (int g = 0; g < 2; g++)
                qf[mi][g] = *(const short8*)(Qh + (size_t)(rb0 + mi * 16 + l15) * HD + g * 32 + quad * 8);

        float4v ov[2][4] = {};                 // O accs: [16-row block][d=dg*16+l15], row=quad*4+r
        float m[2]  = {-1e30f, -1e30f};        // running row max for qrow = l15 (raw score units)
        float lp[2] = {0.f, 0.f};              // running row sum of p~ for qrow = l15
        int ntiles = qt + 1;

        for (int jt = 0; jt < ntiles; jt++) {
            int j0 = jt * 64;
            __syncthreads();
            const unsigned short* Kg = Kh + (size_t)(j0 + srow) * HD + sc;
            const unsigned short* Vg = Vh + (size_t)srow * Tseq + j0 + sc;
            #pragma unroll
            for (int u = 0; u < 4; u++) {
                *(short8*)&Ks[srow * LDK + sc + u * 8] = *(const short8*)(Kg + u * 8);
                *(short8*)&Vs[srow * LDK + sc + u * 8] = *(const short8*)(Vg + u * 8);
            }
            __syncthreads();

            // S^T = K * Q^T  (C-layout: row=key=quad*4+r, col=qrow=l15) — raw scores
            float4v st[2][4];
            #pragma unroll
            for (int mi = 0; mi < 2; mi++)
                #pragma unroll
                for (int kg = 0; kg < 4; kg++)
                    st[mi][kg] = (float4v){0.f, 0.f, 0.f, 0.f};
            #pragma unroll
            for (int g = 0; g < 2; g++) {
                #pragma unroll
                for (int kg = 0; kg < 4; kg++) {
                    short8 kf = *(const short8*)&Ks[(kg * 16 + l15) * LDK + g * 32 + quad * 8];
                    st[0][kg] = __builtin_amdgcn_mfma_f32_16x16x32_bf16(kf, qf[0][g], st[0][kg], 0, 0, 0);
                    st[1][kg] = __builtin_amdgcn_mfma_f32_16x16x32_bf16(kf, qf[1][g], st[1][kg], 0, 0, 0);
                }
            }

            // causal mask: only the diagonal tile needs it
            if (jt == ntiles - 1) {
                #pragma unroll
                for (int mi = 0; mi < 2; mi++) {
                    int qrow = rb0 + mi * 16 + l15;
                    #pragma unroll
                    for (int kg = 0; kg < 4; kg++) {
                        int keyb = j0 + kg * 16 + quad * 4;
                        #pragma unroll
                        for (int r = 0; r < 4; r++)
                            if (keyb + r > qrow) st[mi][kg][r] = -1e30f;
                    }
                }
            }

            // online softmax with row-max (row = qrow = l15 for st)
            short4v pf[2][4];
            float al[2];
            #pragma unroll
            for (int mi = 0; mi < 2; mi++) {
                // tile max for this row, per lane over 16 regs, then across quads
                float mx = st[mi][0][0];
                #pragma unroll
                for (int kg = 0; kg < 4; kg++)
                    #pragma unroll
                    for (int r = 0; r < 4; r++)
                        mx = fmaxf(mx, st[mi][kg][r]);
                mx = fmaxf(mx, __shfl_xor(mx, 16));
                mx = fmaxf(mx, __shfl_xor(mx, 32));
                float mn = fmaxf(m[mi], mx);
                al[mi] = __builtin_amdgcn_exp2f((m[mi] - mn) * cexp);
                m[mi] = mn;
                float sum = 0.f;
                #pragma unroll
                for (int kg = 0; kg < 4; kg++) {
                    unsigned short us[4];
                    #pragma unroll
                    for (int r = 0; r < 4; r++) {
                        float p = __builtin_amdgcn_exp2f((st[mi][kg][r] - mn) * cexp);
                        us[r] = f2b(p);
                        sum += b2f(us[r]);     // l from ROUNDED p: consistent with numerator
                    }
                    union { unsigned u[2]; short4v s; } pk_;
                    pk_.u[0] = (unsigned)us[0] | ((unsigned)us[1] << 16);
                    pk_.u[1] = (unsigned)us[2] | ((unsigned)us[3] << 16);
                    pf[mi][kg] = pk_.s;
                }
                lp[mi] = lp[mi] * al[mi] + sum;
            }

            // rescale O by alpha (alpha indexed by l15; ov rows are quad*4+r)
            #pragma unroll
            for (int mi = 0; mi < 2; mi++) {
                float ar_[4];
                #pragma unroll
                for (int r = 0; r < 4; r++)
                    ar_[r] = __shfl(al[mi], quad * 4 + r);
                #pragma unroll
                for (int dg = 0; dg < 4; dg++)
                    #pragma unroll
                    for (int r = 0; r < 4; r++)
                        ov[mi][dg][r] *= ar_[r];
            }

            // O += P * V   (A = P^T frags from regs, B = V frags from Vs)
            #pragma unroll
            for (int kg = 0; kg < 4; kg++) {
                #pragma unroll
                for (int dg = 0; dg < 4; dg++) {
                    short4v vf = *(const short4v*)&Vs[(dg * 16 + l15) * LDK + kg * 16 + quad * 4];
                    ov[0][dg] = __builtin_amdgcn_mfma_f32_16x16x16bf16_1k(pf[0][kg], vf, ov[0][dg], 0, 0, 0);
                    ov[1][dg] = __builtin_amdgcn_mfma_f32_16x16x16bf16_1k(pf[1][kg], vf, ov[1][dg], 0, 0, 0);
                }
            }
        }

        // epilogue: reduce l across quads, divide, store y[b][t][h*64+d]
        #pragma unroll
        for (int mi = 0; mi < 2; mi++) {
            float lf = lp[mi];
            lf += __shfl_xor(lf, 16);
            lf += __shfl_xor(lf, 32);          // all lanes: full sum for qrow = l15
            float rinv[4];
            #pragma unroll
            for (int r = 0; r < 4; r++)
                rinv[r] = 1.0f / __shfl(lf, quad * 4 + r);
            #pragma unroll
            for (int dg = 0; dg < 4; dg++)
                #pragma unroll
                for (int r = 0; r < 4; r++) {
                    int t = rb0 + mi * 16 + quad * 4 + r;
                    yb[((size_t)b * Tseq + t) * Cdim + h * HD + dg * 16 + l15] =
                        f2b(ov[mi][dg][r] * rinv[r]);
                }
        }
    }
}

extern "C" void kernel_launch(void* const* d_in, const int* in_sizes, int n_in,
                              void* d_out, int out_size, void* d_ws, size_t ws_size,
                              hipStream_t stream) {
    const float* x  = (const float*)d_in[0];
    const float* Wa = (const float*)d_in[1];
    const float* ba = (const float*)d_in[2];
    const float* Wp = (const float*)d_in[3];
    const float* bp = (const float*)d_in[4];
    float* out = (float*)d_out;

    unsigned short* ws = (unsigned short*)d_ws;
    unsigned short* xb  = ws;                          // 8192*1024
    unsigned short* Wat = xb  + (size_t)Mrows * Cdim;  // 3072*1024
    unsigned short* Wpt = Wat + (size_t)N3C * Cdim;    // 1024*1024
    unsigned short* qb  = Wpt + (size_t)Cdim * Cdim;   // [bh][T][HD]
    unsigned short* kb  = qb  + (size_t)Bsz * NH * Tseq * HD;   // [bh][T][HD]
    unsigned short* vb  = kb  + (size_t)Bsz * NH * Tseq * HD;   // [bh][HD][T]  (transposed)
    unsigned short* yb  = vb  + (size_t)Bsz * NH * Tseq * HD;

    int nx = Mrows * Cdim;
    cast_kernel<<<nx / 4 / 256, 256, 0, stream>>>(x, xb, nx);
    transpose_cast<<<dim3(N3C / 32, Cdim / 32), 256, 0, stream>>>(Wa, Wat, Cdim, N3C);
    transpose_cast<<<dim3(Cdim / 32, Cdim / 32), 256, 0, stream>>>(Wp, Wpt, Cdim, Cdim);

    gemm_bt<true><<<dim3(N3C / 128, Mrows / 128), 256, 0, stream>>>(
        xb, Wat, ba, qb, kb, vb, nullptr);

    attn_kernel<<<dim3(16, Bsz * NH), 128, 0, stream>>>(qb, kb, vb, yb);

    gemm_bt<false><<<dim3(Cdim / 128, Mrows / 128), 256, 0, stream>>>(
        yb, Wpt, bp, nullptr, nullptr, nullptr, out);
}

// Round 5
// 310.257 us; speedup vs baseline: 1.7564x; 1.0528x over previous
//
#include <hip/hip_runtime.h>
#include <hip/hip_bf16.h>

// Problem constants
#define Bsz 4
#define Tseq 2048
#define Cdim 1024
#define NH 16
#define HD 64
#define Mrows (Bsz*Tseq)      // 8192
#define N3C (3*Cdim)          // 3072

typedef __attribute__((ext_vector_type(8))) short short8;
typedef __attribute__((ext_vector_type(4))) short short4v;
typedef __attribute__((ext_vector_type(4))) float float4v;

__device__ __forceinline__ unsigned short f2b(float f) {
    union { float f; unsigned u; } x; x.f = f;
    unsigned u = x.u;
    u += 0x7fff + ((u >> 16) & 1);   // true RNE to bf16
    return (unsigned short)(u >> 16);
}

__device__ __forceinline__ float lo_b(unsigned u) {
    union { unsigned x; float f; } c; c.x = u << 16; return c.f;
}
__device__ __forceinline__ float hi_b(unsigned u) {
    union { unsigned x; float f; } c; c.x = u & 0xffff0000u; return c.f;
}

// pack 2 floats -> bf16x2 dword (RNE)
__device__ __forceinline__ unsigned pk2bf(float a, float b) {
#if __has_builtin(__builtin_amdgcn_cvt_pk_bf16_f32)
    auto w = __builtin_amdgcn_cvt_pk_bf16_f32(a, b);
    unsigned u; __builtin_memcpy(&u, &w, 4);
    return u;
#else
    return (unsigned)f2b(a) | ((unsigned)f2b(b) << 16);
#endif
}

// async global->LDS, 16B per lane; lds dst must be wave-uniform (HW adds lane*16)
#define GLDS(gp, lp) __builtin_amdgcn_global_load_lds(                         \
    (const __attribute__((address_space(1))) unsigned*)(gp),                   \
    (__attribute__((address_space(3))) unsigned*)(lp), 16, 0, 0)

// ---------------- cast x: f32 -> bf16 ----------------
__global__ __launch_bounds__(256) void cast_kernel(const float* __restrict__ in,
                                                   unsigned short* __restrict__ out, int n) {
    int i = (blockIdx.x * 256 + threadIdx.x) * 4;
    if (i < n) {
        float4 v = *reinterpret_cast<const float4*>(in + i);
        ushort4 o;
        o.x = f2b(v.x); o.y = f2b(v.y); o.z = f2b(v.z); o.w = f2b(v.w);
        *reinterpret_cast<ushort4*>(out + i) = o;
    }
}

// ---------------- transpose + cast: W[K][N] f32 -> Wt[N][K] bf16 ----------------
__global__ __launch_bounds__(256) void transpose_cast(const float* __restrict__ in,
                                                      unsigned short* __restrict__ out,
                                                      int K, int N) {
    __shared__ float tile[32][33];
    int n0 = blockIdx.x * 32, k0 = blockIdx.y * 32;
    int tx = threadIdx.x & 31, ty = threadIdx.x >> 5;   // 8 rows per pass
    #pragma unroll
    for (int i = 0; i < 32; i += 8)
        tile[ty + i][tx] = in[(k0 + ty + i) * N + n0 + tx];
    __syncthreads();
    #pragma unroll
    for (int i = 0; i < 32; i += 8)
        out[(size_t)(n0 + ty + i) * K + k0 + tx] = f2b(tile[tx][ty + i]);
}

// ---------------- bf16 MFMA GEMM: C[M,N] = A[M,K] * Bt[N,K]^T ----------------
// m97 structure: 128x128 tile, BK=32, global_load_lds dwordx4 staging into
// UNPADDED [128][32] LDS (layout forced by wave-uniform-base + lane*16B rule).
// 4 waves in 2x2, each wave 64x64 (4x4 MFMA 16x16x32).

template<bool QKV>
__global__ __launch_bounds__(256) void gemm_bt(const unsigned short* __restrict__ A,
                                               const unsigned short* __restrict__ Bt,
                                               const float* __restrict__ bias,
                                               unsigned short* __restrict__ qb,
                                               unsigned short* __restrict__ kb,
                                               unsigned short* __restrict__ vb,
                                               float* __restrict__ out) {
    __shared__ unsigned short As[128 * 32];
    __shared__ unsigned short Bs[128 * 32];
    int tid = threadIdx.x;
    int lane = tid & 63, wave = tid >> 6;
    int wm = wave >> 1, wn = wave & 1;
    int l15 = lane & 15, quad = lane >> 4;
    int row0 = blockIdx.y * 128;
    int col0 = blockIdx.x * 128;

    // staging: thread tid -> row tid>>2 (and +64), k-slice (tid&3)*8 (16B)
    int sr = tid >> 2, sk = (tid & 3) * 8;
    const unsigned short* Ag = A + (size_t)(row0 + sr) * Cdim + sk;
    const unsigned short* Bg = Bt + (size_t)(col0 + sr) * Cdim + sk;
    unsigned short* Al = &As[wave * 512];   // wave-uniform dst; lane*16B appended by HW
    unsigned short* Bl = &Bs[wave * 512];

    float4v acc[4][4] = {};

    for (int k0 = 0; k0 < Cdim; k0 += 32) {
        __syncthreads();
        GLDS(Ag + k0,             Al);
        GLDS(Ag + k0 + 64 * Cdim, Al + 2048);
        GLDS(Bg + k0,             Bl);
        GLDS(Bg + k0 + 64 * Cdim, Bl + 2048);
        __syncthreads();   // drains vmcnt -> staged data visible

        short8 af[4], bf[4];
        #pragma unroll
        for (int mi = 0; mi < 4; mi++)
            af[mi] = *(const short8*)&As[(wm * 64 + mi * 16 + l15) * 32 + quad * 8];
        #pragma unroll
        for (int ni = 0; ni < 4; ni++)
            bf[ni] = *(const short8*)&Bs[(wn * 64 + ni * 16 + l15) * 32 + quad * 8];
        #pragma unroll
        for (int mi = 0; mi < 4; mi++)
            #pragma unroll
            for (int ni = 0; ni < 4; ni++)
                acc[mi][ni] = __builtin_amdgcn_mfma_f32_16x16x32_bf16(af[mi], bf[ni], acc[mi][ni], 0, 0, 0);
    }

    // epilogue
    #pragma unroll
    for (int mi = 0; mi < 4; mi++) {
        #pragma unroll
        for (int ni = 0; ni < 4; ni++) {
            #pragma unroll
            for (int r = 0; r < 4; r++) {
                int row = row0 + wm * 64 + mi * 16 + quad * 4 + r;
                int col = col0 + wn * 64 + ni * 16 + l15;
                float v = acc[mi][ni][r] + bias[col];
                if (QKV) {
                    int p = col >> 10;          // 0=q 1=k 2=v
                    int h = (col & 1023) >> 6;
                    int d = col & 63;
                    int b = row >> 11;
                    int t = row & 2047;
                    if (p == 0) {
                        qb[((size_t)(b * NH + h) * Tseq + t) * HD + d] = f2b(v);
                    } else if (p == 1) {
                        kb[((size_t)(b * NH + h) * Tseq + t) * HD + d] = f2b(v);
                    } else {
                        // V stored TRANSPOSED: [bh][d][T]
                        vb[((size_t)(b * NH + h) * HD + d) * Tseq + t] = f2b(v);
                    }
                } else {
                    out[(size_t)row * Cdim + col] = v;
                }
            }
        }
    }
}

// ---------------- flash attention (causal), bf16 MFMA, S^T register trick ----------------
// block = 128 thr (2 waves); block processes q-tile pair (pi, 31-pi), 64 rows each,
// 32 rows/wave; kv tiles of 64 keys. No P LDS round-trip: S^T C-layout matches the
// A-operand layout of mfma_f32_16x16x16bf16_1k, so P goes register->MFMA directly.
// Grid is (bh, pi)-ordered so a head's 16 blocks share id%8 -> same XCD L2.
#define LDK 72   // padded LDS stride (shorts): 144B rows, 16B aligned

__global__ __launch_bounds__(128, 3) void attn_kernel(const unsigned short* __restrict__ qb,
                                                      const unsigned short* __restrict__ kb,
                                                      const unsigned short* __restrict__ vt,
                                                      unsigned short* __restrict__ yb) {
    __shared__ unsigned short Ks[64 * LDK];   // [key][d]
    __shared__ unsigned short Vs[64 * LDK];   // [d][key]  (from pre-transposed global V)

    int tid = threadIdx.x;
    int lane = tid & 63, wave = tid >> 6;      // 2 waves
    int l15 = lane & 15, quad = lane >> 4;
    int bh = blockIdx.x;                       // head id (fast dim -> XCD grouping)
    int pi = blockIdx.y;                       // pair index 0..15

    const unsigned short* Qh = qb + (size_t)bh * Tseq * HD;
    const unsigned short* Kh = kb + (size_t)bh * Tseq * HD;
    const unsigned short* Vh = vt + (size_t)bh * HD * Tseq;
    int b = bh >> 4, h = bh & 15;

    int srow = tid >> 1, sc = (tid & 1) * 32;  // staging: 2 thr/row, 32 shorts each
    const float cexp = 0.18033688011112042f;   // 0.125 * log2(e)

    #pragma unroll 1
    for (int half = 0; half < 2; half++) {
        int qt = half ? (31 - pi) : pi;        // q-tile index 0..31 (64 rows)
        int q0 = qt * 64;
        int rb0 = q0 + wave * 32;              // this wave's 32 q-rows

        // Q fragments (B-operand layout: lane holds Q[qrow=l15][d=quad*8+j])
        short8 qf[2][2];
        #pragma unroll
        for (int mi = 0; mi < 2; mi++)
            #pragma unroll
            for (int g = 0; g < 2; g++)
                qf[mi][g] = *(const short8*)(Qh + (size_t)(rb0 + mi * 16 + l15) * HD + g * 32 + quad * 8);

        float4v ov[2][4] = {};                 // O accs: [16-row block][d=dg*16+l15], row=quad*4+r
        float m[2]  = {-1e30f, -1e30f};        // running row max for qrow = l15 (raw score units)
        float lp[2] = {0.f, 0.f};              // running row sum of p~ for qrow = l15
        int ntiles = qt + 1;

        for (int jt = 0; jt < ntiles; jt++) {
            int j0 = jt * 64;
            __syncthreads();
            const unsigned short* Kg = Kh + (size_t)(j0 + srow) * HD + sc;
            const unsigned short* Vg = Vh + (size_t)srow * Tseq + j0 + sc;
            #pragma unroll
            for (int u = 0; u < 4; u++) {
                *(short8*)&Ks[srow * LDK + sc + u * 8] = *(const short8*)(Kg + u * 8);
                *(short8*)&Vs[srow * LDK + sc + u * 8] = *(const short8*)(Vg + u * 8);
            }
            __syncthreads();

            // S^T = K * Q^T  (C-layout: row=key=quad*4+r, col=qrow=l15) — raw scores
            float4v st[2][4];
            #pragma unroll
            for (int mi = 0; mi < 2; mi++)
                #pragma unroll
                for (int kg = 0; kg < 4; kg++)
                    st[mi][kg] = (float4v){0.f, 0.f, 0.f, 0.f};
            #pragma unroll
            for (int g = 0; g < 2; g++) {
                #pragma unroll
                for (int kg = 0; kg < 4; kg++) {
                    short8 kf = *(const short8*)&Ks[(kg * 16 + l15) * LDK + g * 32 + quad * 8];
                    st[0][kg] = __builtin_amdgcn_mfma_f32_16x16x32_bf16(kf, qf[0][g], st[0][kg], 0, 0, 0);
                    st[1][kg] = __builtin_amdgcn_mfma_f32_16x16x32_bf16(kf, qf[1][g], st[1][kg], 0, 0, 0);
                }
            }

            // causal mask: only the diagonal tile needs it
            if (jt == ntiles - 1) {
                #pragma unroll
                for (int mi = 0; mi < 2; mi++) {
                    int qrow = rb0 + mi * 16 + l15;
                    #pragma unroll
                    for (int kg = 0; kg < 4; kg++) {
                        int keyb = j0 + kg * 16 + quad * 4;
                        #pragma unroll
                        for (int r = 0; r < 4; r++)
                            if (keyb + r > qrow) st[mi][kg][r] = -1e30f;
                    }
                }
            }

            // online softmax with row-max (row = qrow = l15 for st)
            short4v pf[2][4];
            #pragma unroll
            for (int mi = 0; mi < 2; mi++) {
                float mx = st[mi][0][0];
                #pragma unroll
                for (int kg = 0; kg < 4; kg++)
                    #pragma unroll
                    for (int r = 0; r < 4; r++)
                        mx = fmaxf(mx, st[mi][kg][r]);
                mx = fmaxf(mx, __shfl_xor(mx, 16));
                mx = fmaxf(mx, __shfl_xor(mx, 32));
                float mn = fmaxf(m[mi], mx);
                // rescale only when some row's max actually grew (skips most late tiles)
                if (__any(mn > m[mi])) {
                    float alv = __builtin_amdgcn_exp2f((m[mi] - mn) * cexp);
                    m[mi] = mn;
                    lp[mi] *= alv;
                    float ar_[4];
                    #pragma unroll
                    for (int r = 0; r < 4; r++)
                        ar_[r] = __shfl(alv, quad * 4 + r);
                    #pragma unroll
                    for (int dg = 0; dg < 4; dg++)
                        #pragma unroll
                        for (int r = 0; r < 4; r++)
                            ov[mi][dg][r] *= ar_[r];
                }
                float sum = 0.f;
                #pragma unroll
                for (int kg = 0; kg < 4; kg++) {
                    float p0 = __builtin_amdgcn_exp2f((st[mi][kg][0] - m[mi]) * cexp);
                    float p1 = __builtin_amdgcn_exp2f((st[mi][kg][1] - m[mi]) * cexp);
                    float p2 = __builtin_amdgcn_exp2f((st[mi][kg][2] - m[mi]) * cexp);
                    float p3 = __builtin_amdgcn_exp2f((st[mi][kg][3] - m[mi]) * cexp);
                    unsigned u0 = pk2bf(p0, p1);
                    unsigned u1 = pk2bf(p2, p3);
                    // l from ROUNDED p: numerator/denominator consistent
                    sum += (lo_b(u0) + hi_b(u0)) + (lo_b(u1) + hi_b(u1));
                    union { unsigned u[2]; short4v s; } pk_;
                    pk_.u[0] = u0; pk_.u[1] = u1;
                    pf[mi][kg] = pk_.s;
                }
                lp[mi] += sum;
            }

            // O += P * V   (A = P^T frags from regs, B = V frags from Vs)
            #pragma unroll
            for (int kg = 0; kg < 4; kg++) {
                #pragma unroll
                for (int dg = 0; dg < 4; dg++) {
                    short4v vf = *(const short4v*)&Vs[(dg * 16 + l15) * LDK + kg * 16 + quad * 4];
                    ov[0][dg] = __builtin_amdgcn_mfma_f32_16x16x16bf16_1k(pf[0][kg], vf, ov[0][dg], 0, 0, 0);
                    ov[1][dg] = __builtin_amdgcn_mfma_f32_16x16x16bf16_1k(pf[1][kg], vf, ov[1][dg], 0, 0, 0);
                }
            }
        }

        // epilogue: reduce l across quads, divide, store y[b][t][h*64+d]
        #pragma unroll
        for (int mi = 0; mi < 2; mi++) {
            float lf = lp[mi];
            lf += __shfl_xor(lf, 16);
            lf += __shfl_xor(lf, 32);          // all lanes: full sum for qrow = l15
            float rinv[4];
            #pragma unroll
            for (int r = 0; r < 4; r++)
                rinv[r] = 1.0f / __shfl(lf, quad * 4 + r);
            #pragma unroll
            for (int dg = 0; dg < 4; dg++)
                #pragma unroll
                for (int r = 0; r < 4; r++) {
                    int t = rb0 + mi * 16 + quad * 4 + r;
                    yb[((size_t)b * Tseq + t) * Cdim + h * HD + dg * 16 + l15] =
                        f2b(ov[mi][dg][r] * rinv[r]);
                }
        }
    }
}

extern "C" void kernel_launch(void* const* d_in, const int* in_sizes, int n_in,
                              void* d_out, int out_size, void* d_ws, size_t ws_size,
                              hipStream_t stream) {
    const float* x  = (const float*)d_in[0];
    const float* Wa = (const float*)d_in[1];
    const float* ba = (const float*)d_in[2];
    const float* Wp = (const float*)d_in[3];
    const float* bp = (const float*)d_in[4];
    float* out = (float*)d_out;

    unsigned short* ws = (unsigned short*)d_ws;
    unsigned short* xb  = ws;                          // 8192*1024
    unsigned short* Wat = xb  + (size_t)Mrows * Cdim;  // 3072*1024
    unsigned short* Wpt = Wat + (size_t)N3C * Cdim;    // 1024*1024
    unsigned short* qb  = Wpt + (size_t)Cdim * Cdim;   // [bh][T][HD]
    unsigned short* kb  = qb  + (size_t)Bsz * NH * Tseq * HD;   // [bh][T][HD]
    unsigned short* vb  = kb  + (size_t)Bsz * NH * Tseq * HD;   // [bh][HD][T]  (transposed)
    unsigned short* yb  = vb  + (size_t)Bsz * NH * Tseq * HD;

    int nx = Mrows * Cdim;
    cast_kernel<<<nx / 4 / 256, 256, 0, stream>>>(x, xb, nx);
    transpose_cast<<<dim3(N3C / 32, Cdim / 32), 256, 0, stream>>>(Wa, Wat, Cdim, N3C);
    transpose_cast<<<dim3(Cdim / 32, Cdim / 32), 256, 0, stream>>>(Wp, Wpt, Cdim, Cdim);

    gemm_bt<true><<<dim3(N3C / 128, Mrows / 128), 256, 0, stream>>>(
        xb, Wat, ba, qb, kb, vb, nullptr);

    attn_kernel<<<dim3(Bsz * NH, 16), 128, 0, stream>>>(qb, kb, vb, yb);

    gemm_bt<false><<<dim3(Cdim / 128, Mrows / 128), 256, 0, stream>>>(
        yb, Wpt, bp, nullptr, nullptr, nullptr, out);
}

// Round 6
// 291.677 us; speedup vs baseline: 1.8683x; 1.0637x over previous
//
#include <hip/hip_runtime.h>
#include <hip/hip_bf16.h>

// Problem constants
#define Bsz 4
#define Tseq 2048
#define Cdim 1024
#define NH 16
#define HD 64
#define Mrows (Bsz*Tseq)      // 8192
#define N3C (3*Cdim)          // 3072

typedef __attribute__((ext_vector_type(8))) short short8;
typedef __attribute__((ext_vector_type(4))) short short4v;
typedef __attribute__((ext_vector_type(4))) float float4v;

__device__ __forceinline__ unsigned short f2b(float f) {
    union { float f; unsigned u; } x; x.f = f;
    unsigned u = x.u;
    u += 0x7fff + ((u >> 16) & 1);   // true RNE to bf16
    return (unsigned short)(u >> 16);
}

__device__ __forceinline__ float lo_b(unsigned u) {
    union { unsigned x; float f; } c; c.x = u << 16; return c.f;
}
__device__ __forceinline__ float hi_b(unsigned u) {
    union { unsigned x; float f; } c; c.x = u & 0xffff0000u; return c.f;
}

// pack 2 floats -> bf16x2 dword (RNE)
__device__ __forceinline__ unsigned pk2bf(float a, float b) {
#if __has_builtin(__builtin_amdgcn_cvt_pk_bf16_f32)
    auto w = __builtin_amdgcn_cvt_pk_bf16_f32(a, b);
    unsigned u; __builtin_memcpy(&u, &w, 4);
    return u;
#else
    return (unsigned)f2b(a) | ((unsigned)f2b(b) << 16);
#endif
}

// async global->LDS, 16B per lane; lds dst must be wave-uniform (HW adds lane*16)
#define GLDS(gp, lp) __builtin_amdgcn_global_load_lds(                         \
    (const __attribute__((address_space(1))) unsigned*)(gp),                   \
    (__attribute__((address_space(3))) unsigned*)(lp), 16, 0, 0)

// ---------------- cast x: f32 -> bf16 ----------------
__global__ __launch_bounds__(256) void cast_kernel(const float* __restrict__ in,
                                                   unsigned short* __restrict__ out, int n) {
    int i = (blockIdx.x * 256 + threadIdx.x) * 4;
    if (i < n) {
        float4 v = *reinterpret_cast<const float4*>(in + i);
        ushort4 o;
        o.x = f2b(v.x); o.y = f2b(v.y); o.z = f2b(v.z); o.w = f2b(v.w);
        *reinterpret_cast<ushort4*>(out + i) = o;
    }
}

// ---------------- transpose + cast: W[K][N] f32 -> Wt[N][K] bf16 ----------------
__global__ __launch_bounds__(256) void transpose_cast(const float* __restrict__ in,
                                                      unsigned short* __restrict__ out,
                                                      int K, int N) {
    __shared__ float tile[32][33];
    int n0 = blockIdx.x * 32, k0 = blockIdx.y * 32;
    int tx = threadIdx.x & 31, ty = threadIdx.x >> 5;   // 8 rows per pass
    #pragma unroll
    for (int i = 0; i < 32; i += 8)
        tile[ty + i][tx] = in[(k0 + ty + i) * N + n0 + tx];
    __syncthreads();
    #pragma unroll
    for (int i = 0; i < 32; i += 8)
        out[(size_t)(n0 + ty + i) * K + k0 + tx] = f2b(tile[tx][ty + i]);
}

// ---------------- bf16 MFMA GEMM: C[M,N] = A[M,K] * Bt[N,K]^T ----------------
// m97 structure: 128x128 tile, BK=32, global_load_lds dwordx4 staging into
// UNPADDED [128][32] LDS. 1D grid with XCD-panel swizzle: XCD x owns row-blocks
// [8x, 8x+8) x all cols -> A panel (2 MB) stays in that XCD's L2, B streams.

template<bool QKV, int NCOL>
__global__ __launch_bounds__(256) void gemm_bt(const unsigned short* __restrict__ A,
                                               const unsigned short* __restrict__ Bt,
                                               const float* __restrict__ bias,
                                               unsigned short* __restrict__ qb,
                                               unsigned short* __restrict__ kb,
                                               unsigned short* __restrict__ vb,
                                               float* __restrict__ out) {
    __shared__ unsigned short As[128 * 32];
    __shared__ unsigned short Bs[128 * 32];
    int tid = threadIdx.x;
    int lane = tid & 63, wave = tid >> 6;
    int wm = wave >> 1, wn = wave & 1;
    int l15 = lane & 15, quad = lane >> 4;

    // XCD-panel swizzle (blocks dispatch round-robin to XCDs by flat id % 8)
    int f = blockIdx.x;
    int xcd = f & 7, slot = f >> 3;
    int rowblk = xcd * 8 + (slot & 7);   // 64 row-blocks: 8 per XCD
    int colblk = slot >> 3;              // 0..NCOL-1
    int row0 = rowblk * 128;
    int col0 = colblk * 128;

    // staging: thread tid -> row tid>>2 (and +64), k-slice (tid&3)*8 (16B)
    int sr = tid >> 2, sk = (tid & 3) * 8;
    const unsigned short* Ag = A + (size_t)(row0 + sr) * Cdim + sk;
    const unsigned short* Bg = Bt + (size_t)(col0 + sr) * Cdim + sk;
    unsigned short* Al = &As[wave * 512];   // wave-uniform dst; lane*16B appended by HW
    unsigned short* Bl = &Bs[wave * 512];

    float4v acc[4][4] = {};

    for (int k0 = 0; k0 < Cdim; k0 += 32) {
        __syncthreads();
        GLDS(Ag + k0,             Al);
        GLDS(Ag + k0 + 64 * Cdim, Al + 2048);
        GLDS(Bg + k0,             Bl);
        GLDS(Bg + k0 + 64 * Cdim, Bl + 2048);
        __syncthreads();   // drains vmcnt -> staged data visible

        short8 af[4], bf[4];
        #pragma unroll
        for (int mi = 0; mi < 4; mi++)
            af[mi] = *(const short8*)&As[(wm * 64 + mi * 16 + l15) * 32 + quad * 8];
        #pragma unroll
        for (int ni = 0; ni < 4; ni++)
            bf[ni] = *(const short8*)&Bs[(wn * 64 + ni * 16 + l15) * 32 + quad * 8];
        #pragma unroll
        for (int mi = 0; mi < 4; mi++)
            #pragma unroll
            for (int ni = 0; ni < 4; ni++)
                acc[mi][ni] = __builtin_amdgcn_mfma_f32_16x16x32_bf16(af[mi], bf[ni], acc[mi][ni], 0, 0, 0);
    }

    // epilogue
    #pragma unroll
    for (int mi = 0; mi < 4; mi++) {
        #pragma unroll
        for (int ni = 0; ni < 4; ni++) {
            int colb = col0 + wn * 64 + ni * 16 + l15;
            int rowb = row0 + wm * 64 + mi * 16 + quad * 4;
            if (QKV) {
                int p = colb >> 10;          // 0=q 1=k 2=v
                int h = (colb & 1023) >> 6;
                int d = colb & 63;
                int b = rowb >> 11;
                int t = rowb & 2047;
                if (p == 2) {
                    // V transposed [bh][d][T]: r-values are t-consecutive -> ushort4
                    ushort4 pk;
                    pk.x = f2b(acc[mi][ni][0] + bias[colb]);
                    pk.y = f2b(acc[mi][ni][1] + bias[colb]);
                    pk.z = f2b(acc[mi][ni][2] + bias[colb]);
                    pk.w = f2b(acc[mi][ni][3] + bias[colb]);
                    *(ushort4*)&vb[((size_t)(b * NH + h) * HD + d) * Tseq + t] = pk;
                } else {
                    unsigned short* dst = (p == 0) ? qb : kb;
                    #pragma unroll
                    for (int r = 0; r < 4; r++)
                        dst[((size_t)(b * NH + h) * Tseq + (t + r)) * HD + d] =
                            f2b(acc[mi][ni][r] + bias[colb]);
                }
            } else {
                #pragma unroll
                for (int r = 0; r < 4; r++)
                    out[(size_t)(rowb + r) * Cdim + colb] = acc[mi][ni][r] + bias[colb];
            }
        }
    }
}

// ---------------- flash attention (causal), bf16 MFMA, S^T register trick ----------------
// block = 128 thr (2 waves); block handles ONE 64-row q-tile (32 rows/wave);
// kv tiles of 64 keys. Grid (bh=64 fast, qt=32): bh%8 -> XCD groups heads for L2;
// qt reversed so heavy blocks dispatch first. 2048 blocks -> 16 waves/CU.
#define LDK 72   // padded LDS stride (shorts): 144B rows, 16B aligned

__global__ __launch_bounds__(128, 4) void attn_kernel(const unsigned short* __restrict__ qb,
                                                      const unsigned short* __restrict__ kb,
                                                      const unsigned short* __restrict__ vt,
                                                      unsigned short* __restrict__ yb) {
    __shared__ unsigned short Ks[64 * LDK];   // [key][d]
    __shared__ unsigned short Vs[64 * LDK];   // [d][key]  (from pre-transposed global V)

    int tid = threadIdx.x;
    int lane = tid & 63, wave = tid >> 6;      // 2 waves
    int l15 = lane & 15, quad = lane >> 4;
    int bh = blockIdx.x;                       // head id (fast dim -> XCD grouping)
    int qt = 31 - blockIdx.y;                  // heavy q-tiles dispatch first

    const unsigned short* Qh = qb + (size_t)bh * Tseq * HD;
    const unsigned short* Kh = kb + (size_t)bh * Tseq * HD;
    const unsigned short* Vh = vt + (size_t)bh * HD * Tseq;
    int b = bh >> 4, h = bh & 15;

    int srow = tid >> 1, sc = (tid & 1) * 32;  // staging: 2 thr/row, 32 shorts each
    const float cexp = 0.18033688011112042f;   // 0.125 * log2(e)

    int q0 = qt * 64;
    int rb0 = q0 + wave * 32;                  // this wave's 32 q-rows

    // Q fragments (B-operand layout: lane holds Q[qrow=l15][d=quad*8+j])
    short8 qf[2][2];
    #pragma unroll
    for (int mi = 0; mi < 2; mi++)
        #pragma unroll
        for (int g = 0; g < 2; g++)
            qf[mi][g] = *(const short8*)(Qh + (size_t)(rb0 + mi * 16 + l15) * HD + g * 32 + quad * 8);

    float4v ov[2][4] = {};                 // O accs: [16-row block][d=dg*16+l15], row=quad*4+r
    float m[2]  = {-1e30f, -1e30f};        // running row max for qrow = l15 (raw score units)
    float lp[2] = {0.f, 0.f};              // running row sum of p~ for qrow = l15
    int ntiles = qt + 1;

    for (int jt = 0; jt < ntiles; jt++) {
        int j0 = jt * 64;
        __syncthreads();
        const unsigned short* Kg = Kh + (size_t)(j0 + srow) * HD + sc;
        const unsigned short* Vg = Vh + (size_t)srow * Tseq + j0 + sc;
        #pragma unroll
        for (int u = 0; u < 4; u++) {
            *(short8*)&Ks[srow * LDK + sc + u * 8] = *(const short8*)(Kg + u * 8);
            *(short8*)&Vs[srow * LDK + sc + u * 8] = *(const short8*)(Vg + u * 8);
        }
        __syncthreads();

        // S^T = K * Q^T  (C-layout: row=key=quad*4+r, col=qrow=l15) — raw scores
        float4v st[2][4];
        #pragma unroll
        for (int mi = 0; mi < 2; mi++)
            #pragma unroll
            for (int kg = 0; kg < 4; kg++)
                st[mi][kg] = (float4v){0.f, 0.f, 0.f, 0.f};
        #pragma unroll
        for (int g = 0; g < 2; g++) {
            #pragma unroll
            for (int kg = 0; kg < 4; kg++) {
                short8 kf = *(const short8*)&Ks[(kg * 16 + l15) * LDK + g * 32 + quad * 8];
                st[0][kg] = __builtin_amdgcn_mfma_f32_16x16x32_bf16(kf, qf[0][g], st[0][kg], 0, 0, 0);
                st[1][kg] = __builtin_amdgcn_mfma_f32_16x16x32_bf16(kf, qf[1][g], st[1][kg], 0, 0, 0);
            }
        }

        // causal mask: only the diagonal tile needs it
        if (jt == ntiles - 1) {
            #pragma unroll
            for (int mi = 0; mi < 2; mi++) {
                int qrow = rb0 + mi * 16 + l15;
                #pragma unroll
                for (int kg = 0; kg < 4; kg++) {
                    int keyb = j0 + kg * 16 + quad * 4;
                    #pragma unroll
                    for (int r = 0; r < 4; r++)
                        if (keyb + r > qrow) st[mi][kg][r] = -1e30f;
                }
            }
        }

        // online softmax with row-max (row = qrow = l15 for st)
        short4v pf[2][4];
        #pragma unroll
        for (int mi = 0; mi < 2; mi++) {
            float mx = st[mi][0][0];
            #pragma unroll
            for (int kg = 0; kg < 4; kg++)
                #pragma unroll
                for (int r = 0; r < 4; r++)
                    mx = fmaxf(mx, st[mi][kg][r]);
            mx = fmaxf(mx, __shfl_xor(mx, 16));
            mx = fmaxf(mx, __shfl_xor(mx, 32));
            float mn = fmaxf(m[mi], mx);
            // rescale only when some row's max actually grew (skips most late tiles)
            if (__any(mn > m[mi])) {
                float alv = __builtin_amdgcn_exp2f((m[mi] - mn) * cexp);
                m[mi] = mn;
                lp[mi] *= alv;
                float ar_[4];
                #pragma unroll
                for (int r = 0; r < 4; r++)
                    ar_[r] = __shfl(alv, quad * 4 + r);
                #pragma unroll
                for (int dg = 0; dg < 4; dg++)
                    #pragma unroll
                    for (int r = 0; r < 4; r++)
                        ov[mi][dg][r] *= ar_[r];
            }
            float sum = 0.f;
            #pragma unroll
            for (int kg = 0; kg < 4; kg++) {
                float p0 = __builtin_amdgcn_exp2f((st[mi][kg][0] - m[mi]) * cexp);
                float p1 = __builtin_amdgcn_exp2f((st[mi][kg][1] - m[mi]) * cexp);
                float p2 = __builtin_amdgcn_exp2f((st[mi][kg][2] - m[mi]) * cexp);
                float p3 = __builtin_amdgcn_exp2f((st[mi][kg][3] - m[mi]) * cexp);
                unsigned u0 = pk2bf(p0, p1);
                unsigned u1 = pk2bf(p2, p3);
                // l from ROUNDED p: numerator/denominator consistent
                sum += (lo_b(u0) + hi_b(u0)) + (lo_b(u1) + hi_b(u1));
                union { unsigned u[2]; short4v s; } pk_;
                pk_.u[0] = u0; pk_.u[1] = u1;
                pf[mi][kg] = pk_.s;
            }
            lp[mi] += sum;
        }

        // O += P * V   (A = P^T frags from regs, B = V frags from Vs)
        #pragma unroll
        for (int kg = 0; kg < 4; kg++) {
            #pragma unroll
            for (int dg = 0; dg < 4; dg++) {
                short4v vf = *(const short4v*)&Vs[(dg * 16 + l15) * LDK + kg * 16 + quad * 4];
                ov[0][dg] = __builtin_amdgcn_mfma_f32_16x16x16bf16_1k(pf[0][kg], vf, ov[0][dg], 0, 0, 0);
                ov[1][dg] = __builtin_amdgcn_mfma_f32_16x16x16bf16_1k(pf[1][kg], vf, ov[1][dg], 0, 0, 0);
            }
        }
    }

    // epilogue: reduce l across quads, divide, store y[b][t][h*64+d]
    #pragma unroll
    for (int mi = 0; mi < 2; mi++) {
        float lf = lp[mi];
        lf += __shfl_xor(lf, 16);
        lf += __shfl_xor(lf, 32);          // all lanes: full sum for qrow = l15
        float rinv[4];
        #pragma unroll
        for (int r = 0; r < 4; r++)
            rinv[r] = 1.0f / __shfl(lf, quad * 4 + r);
        #pragma unroll
        for (int dg = 0; dg < 4; dg++)
            #pragma unroll
            for (int r = 0; r < 4; r++) {
                int t = rb0 + mi * 16 + quad * 4 + r;
                yb[((size_t)b * Tseq + t) * Cdim + h * HD + dg * 16 + l15] =
                    f2b(ov[mi][dg][r] * rinv[r]);
            }
    }
}

extern "C" void kernel_launch(void* const* d_in, const int* in_sizes, int n_in,
                              void* d_out, int out_size, void* d_ws, size_t ws_size,
                              hipStream_t stream) {
    const float* x  = (const float*)d_in[0];
    const float* Wa = (const float*)d_in[1];
    const float* ba = (const float*)d_in[2];
    const float* Wp = (const float*)d_in[3];
    const float* bp = (const float*)d_in[4];
    float* out = (float*)d_out;

    unsigned short* ws = (unsigned short*)d_ws;
    unsigned short* xb  = ws;                          // 8192*1024
    unsigned short* Wat = xb  + (size_t)Mrows * Cdim;  // 3072*1024
    unsigned short* Wpt = Wat + (size_t)N3C * Cdim;    // 1024*1024
    unsigned short* qb  = Wpt + (size_t)Cdim * Cdim;   // [bh][T][HD]
    unsigned short* kb  = qb  + (size_t)Bsz * NH * Tseq * HD;   // [bh][T][HD]
    unsigned short* vb  = kb  + (size_t)Bsz * NH * Tseq * HD;   // [bh][HD][T]  (transposed)
    unsigned short* yb  = vb  + (size_t)Bsz * NH * Tseq * HD;

    int nx = Mrows * Cdim;
    cast_kernel<<<nx / 4 / 256, 256, 0, stream>>>(x, xb, nx);
    transpose_cast<<<dim3(N3C / 32, Cdim / 32), 256, 0, stream>>>(Wa, Wat, Cdim, N3C);
    transpose_cast<<<dim3(Cdim / 32, Cdim / 32), 256, 0, stream>>>(Wp, Wpt, Cdim, Cdim);

    gemm_bt<true, 24><<<64 * 24, 256, 0, stream>>>(
        xb, Wat, ba, qb, kb, vb, nullptr);

    attn_kernel<<<dim3(Bsz * NH, 32), 128, 0, stream>>>(qb, kb, vb, yb);

    gemm_bt<false, 8><<<64 * 8, 256, 0, stream>>>(
        yb, Wpt, bp, nullptr, nullptr, nullptr, out);
}